// Round 22
// baseline (130.135 us; speedup 1.0000x reference)
//
#include <hip/hip_runtime.h>
#include <hip/hip_bf16.h>

#define NN 8192
#define DD 256
#define BM 128
#define BN 128
#define BK 32

typedef _Float16 f16x8 __attribute__((ext_vector_type(8)));
typedef float f32x4 __attribute__((ext_vector_type(4)));

__device__ inline void gload_lds16(const void* g, void* l) {
  __builtin_amdgcn_global_load_lds(
      (const __attribute__((address_space(1))) void*)g,
      (__attribute__((address_space(3))) void*)l, 16, 0, 0);
}

__device__ __forceinline__ float bfbits2f(unsigned short u) {
  return __uint_as_float(((unsigned)u) << 16);
}

// ---------------- prep: rnorm + f16 cast ----------------
__global__ __launch_bounds__(256) void prep_kernel(
    const float* __restrict__ Z,
    unsigned short* __restrict__ Zh,   // f16 bits
    float* __restrict__ rnorm) {
  const int gtid = blockIdx.x * 256 + threadIdx.x;
  const int row  = gtid >> 6;          // one wave per row
  const int lane = threadIdx.x & 63;
  if (row >= NN) return;

  const float4 v = reinterpret_cast<const float4*>(Z + (size_t)row * DD)[lane];
  float ss = v.x * v.x + v.y * v.y + v.z * v.z + v.w * v.w;
#pragma unroll
  for (int off = 32; off > 0; off >>= 1) ss += __shfl_xor(ss, off);
  if (lane == 0) rnorm[row] = 1.0f / fmaxf(sqrtf(ss), 1e-8f);

  const float f[4] = {v.x, v.y, v.z, v.w};
  unsigned short h[4];
#pragma unroll
  for (int i = 0; i < 4; ++i) {
    _Float16 x = (_Float16)f[i];       // RNE
    h[i] = *reinterpret_cast<unsigned short*>(&x);
  }
  reinterpret_cast<ushort4*>(Zh + (size_t)row * DD)[lane] =
      make_ushort4(h[0], h[1], h[2], h[3]);
}

// LDS: f16 staging (16 KB) union'd with bf16 wave-private transpose buffers
struct __attribute__((aligned(16))) SharedT {
  union {
    struct {
      unsigned short Ah[BM * BK];     // f16 bits, 8 KB
      unsigned short Bh[BN * BK];     // 8 KB
    } t;
    unsigned short tbuf[4][32][68];   // bf16 bits; 17.4 KB
  };
};

// --- upper-tri Gram GEMM (single f16 MFMA pass) + NT dual epilogue;
//     S computed only where the sorted-batch ranges can overlap, zeros else --
__global__ __launch_bounds__(256, 2) void gram_kernel(
    const unsigned short* __restrict__ Zh,
    const float* __restrict__ rnorm,
    const int* __restrict__ batch,
    float* __restrict__ outA,
    float* __restrict__ outS) {
  __shared__ SharedT sh;
  __shared__ float sRnA[BM];
  __shared__ float sRnB[BN];
  __shared__ int   sBtA[BM];
  __shared__ int   sBtB[BN];

  const int tid  = threadIdx.x;
  const int lane = tid & 63;
  const int wid  = tid >> 6;
  const int wr   = wid >> 1;   // 2x2 wave grid, each wave 64x64
  const int wc   = wid & 1;

  // XCD-aware swizzle (2080 % 8 == 0 -> bijective)
  const int nb  = NN / BM;                 // 64
  const int nwg = nb * (nb + 1) / 2;       // 2080
  const int bid = blockIdx.x;
  const int idx = (bid & 7) * (nwg >> 3) + (bid >> 3);

  // triangular decode: idx -> (brow <= bcol)
  int bcol = (int)((sqrtf(8.0f * (float)idx + 1.0f) - 1.0f) * 0.5f);
  while ((bcol + 1) * (bcol + 2) / 2 <= idx) ++bcol;
  while (bcol * (bcol + 1) / 2 > idx) --bcol;
  const int brow = idx - bcol * (bcol + 1) / 2;
  const int row0 = brow * BM, col0 = bcol * BN;

  // sorted batch: same-batch pair exists iff row-range max >= col-range min
  const bool hasS = (batch[row0 + BM - 1] >= batch[col0]);

  if (tid < 128) {
    sRnA[tid] = rnorm[row0 + tid];
    sBtA[tid] = batch[row0 + tid];
  } else {
    const int t = tid - 128;
    sRnB[t] = rnorm[col0 + t];
    sBtB[t] = batch[col0 + t];
  }

  f32x4 acc[4][4] = {};

  const int lr = lane >> 4;   // 0..3  (k-chunk)
  const int lc = lane & 15;   // 0..15 (row within fragment)

  for (int kt = 0; kt < DD / BK; ++kt) {
    const int k0 = kt * BK;
    // stage 2 tiles of 128x32 f16, XOR-swizzled on the GLOBAL side
#pragma unroll
    for (int c = 0; c < 2; ++c) {
      const int ci  = c * 256 + tid;            // 16B-chunk index [0,512)
      const int r   = ci >> 2;                  // tile-local row
      const int ch  = ci & 3;
      const int chg = ch ^ ((r >> 1) & 3);      // swizzle involution
      const int base = (c * 256 + wid * 64) * 16;  // wave-uniform LDS byte base
      const size_t ga = (size_t)(row0 + r) * DD + k0 + chg * 8;
      const size_t gb = (size_t)(col0 + r) * DD + k0 + chg * 8;
      gload_lds16(Zh + ga, (char*)sh.t.Ah + base);
      gload_lds16(Zh + gb, (char*)sh.t.Bh + base);
    }
    __syncthreads();   // drains vmcnt before any wave reads LDS

    // single-pass f16 MFMA (exact products, f32 accumulate)
    f16x8 fa[4], fb[4];
#pragma unroll
    for (int m = 0; m < 4; ++m) {
      const int rA = wr * 64 + m * 16 + lc;
      const int off = rA * BK + ((lr ^ ((rA >> 1) & 3)) << 3);
      fa[m] = *reinterpret_cast<const f16x8*>(&sh.t.Ah[off]);
    }
#pragma unroll
    for (int n = 0; n < 4; ++n) {
      const int rB = wc * 64 + n * 16 + lc;
      const int off = rB * BK + ((lr ^ ((rB >> 1) & 3)) << 3);
      fb[n] = *reinterpret_cast<const f16x8*>(&sh.t.Bh[off]);
    }
#pragma unroll
    for (int m = 0; m < 4; ++m)
#pragma unroll
      for (int n = 0; n < 4; ++n)
        acc[m][n] = __builtin_amdgcn_mfma_f32_16x16x32_f16(fa[m], fb[n], acc[m][n], 0, 0, 0);
    __syncthreads();   // staging consumed; also protects tbuf overlay below
  }

  const bool mirror = (brow != bcol);

  // Barrier-free epilogue: 2 passes of 32 rows; bf16 parking, f32x4 NT stores.
  unsigned short* T = &sh.tbuf[wid][0][0];   // [32][68] bf16 bits

  for (int p = 0; p < 2; ++p) {
    // dump 32x64 (acc m = 2p, 2p+1) as bf16 (RNE)
#pragma unroll
    for (int mm = 0; mm < 2; ++mm) {
#pragma unroll
      for (int n = 0; n < 4; ++n)
#pragma unroll
        for (int j = 0; j < 4; ++j) {
          __hip_bfloat16 h = __float2bfloat16(acc[p * 2 + mm][n][j]);
          T[(mm * 16 + lr * 4 + j) * 68 + n * 16 + lc] =
              *reinterpret_cast<unsigned short*>(&h);
        }
    }
    // (same-wave ds_write->ds_read: compiler inserts lgkmcnt; no barrier)

    // phase A: 4 rows x 64 cols per iter; 256B contiguous per 16-lane group
#pragma unroll 4
    for (int i = 0; i < 8; ++i) {
      const int r  = i * 4 + (lane >> 4);        // 0..31
      const int c4 = (lane & 15) * 4;            // 0,4,...,60
      const int rl = wr * 64 + p * 32 + r;
      const int cl = wc * 64 + c4;
      const ushort4 gu = *reinterpret_cast<const ushort4*>(&T[r * 68 + c4]);
      const float gv[4] = {bfbits2f(gu.x), bfbits2f(gu.y),
                           bfbits2f(gu.z), bfbits2f(gu.w)};
      f32x4 a4;
#pragma unroll
      for (int k = 0; k < 4; ++k)
        a4[k] = __builtin_amdgcn_rcpf(1.0f + __expf(-gv[k]));
      f32x4 s4 = {0.0f, 0.0f, 0.0f, 0.0f};
      if (hasS) {   // block-uniform branch
        const float4 rnB = *reinterpret_cast<const float4*>(&sRnB[cl]);
        const int4   btB = *reinterpret_cast<const int4*>(&sBtB[cl]);
        const float rnA = sRnA[rl];
        const int   btA = sBtA[rl];
        const int   bb[4] = {btB.x, btB.y, btB.z, btB.w};
        const float rb[4] = {rnB.x, rnB.y, rnB.z, rnB.w};
#pragma unroll
        for (int k = 0; k < 4; ++k)
          s4[k] = (btA == bb[k]) ? gv[k] * rnA * rb[k] : 0.0f;
      }
      const size_t o = (size_t)(row0 + rl) * NN + (col0 + cl);
      __builtin_nontemporal_store(a4, reinterpret_cast<f32x4*>(outA + o));
      __builtin_nontemporal_store(s4, reinterpret_cast<f32x4*>(outS + o));
    }

    // phase B: mirrored; 8-lane groups write 128B full lines as f32x4
    if (mirror) {
#pragma unroll 4
      for (int i = 0; i < 8; ++i) {
        const int c  = i * 8 + (lane >> 3);      // orig col (mirror row) 0..63
        const int r4 = (lane & 7) * 4;           // orig row base 0..28
        const int rl = wr * 64 + p * 32 + r4;
        const int cl = wc * 64 + c;
        float gv[4];
#pragma unroll
        for (int k = 0; k < 4; ++k) gv[k] = bfbits2f(T[(r4 + k) * 68 + c]);
        f32x4 a4;
#pragma unroll
        for (int k = 0; k < 4; ++k)
          a4[k] = __builtin_amdgcn_rcpf(1.0f + __expf(-gv[k]));
        f32x4 s4 = {0.0f, 0.0f, 0.0f, 0.0f};
        if (hasS) {
          const float4 rnA4 = *reinterpret_cast<const float4*>(&sRnA[rl]);
          const int4   btA4 = *reinterpret_cast<const int4*>(&sBtA[rl]);
          const float rnB = sRnB[cl];
          const int   btB = sBtB[cl];
          const int   ba[4] = {btA4.x, btA4.y, btA4.z, btA4.w};
          const float ra[4] = {rnA4.x, rnA4.y, rnA4.z, rnA4.w};
#pragma unroll
          for (int k = 0; k < 4; ++k)
            s4[k] = (ba[k] == btB) ? gv[k] * ra[k] * rnB : 0.0f;
        }
        const size_t o = (size_t)(col0 + cl) * NN + (row0 + rl);
        __builtin_nontemporal_store(a4, reinterpret_cast<f32x4*>(outA + o));
        __builtin_nontemporal_store(s4, reinterpret_cast<f32x4*>(outS + o));
      }
    }
  }
}

extern "C" void kernel_launch(void* const* d_in, const int* in_sizes, int n_in,
                              void* d_out, int out_size, void* d_ws, size_t ws_size,
                              hipStream_t stream) {
  const float* Z     = (const float*)d_in[0];
  const int*   batch = (const int*)d_in[1];
  float* out  = (float*)d_out;
  float* outS = out + (size_t)NN * NN;

  unsigned short* Zh = (unsigned short*)d_ws;            // f16 bits, 4 MB
  float* rnorm = (float*)(Zh + (size_t)NN * DD);

  prep_kernel<<<NN / 4, 256, 0, stream>>>(Z, Zh, rnorm);

  const int nb = NN / BM;                 // 64
  const int nblocks = nb * (nb + 1) / 2;  // 2080
  gram_kernel<<<dim3(nblocks), 256, 0, stream>>>(Zh, rnorm, batch, out, outS);
}

// Round 23
// 126.860 us; speedup vs baseline: 1.0258x; 1.0258x over previous
//
#include <hip/hip_runtime.h>
#include <hip/hip_bf16.h>

#define NN 8192
#define DD 256
#define BM 128
#define BN 128
#define BK 32

typedef _Float16 f16x8 __attribute__((ext_vector_type(8)));
typedef float f32x4 __attribute__((ext_vector_type(4)));

__device__ inline void gload_lds16(const void* g, void* l) {
  __builtin_amdgcn_global_load_lds(
      (const __attribute__((address_space(1))) void*)g,
      (__attribute__((address_space(3))) void*)l, 16, 0, 0);
}

__device__ __forceinline__ float bfbits2f(unsigned short u) {
  return __uint_as_float(((unsigned)u) << 16);
}

// ---------------- prep: rnorm + f16 cast ----------------
__global__ __launch_bounds__(256) void prep_kernel(
    const float* __restrict__ Z,
    unsigned short* __restrict__ Zh,   // f16 bits
    float* __restrict__ rnorm) {
  const int gtid = blockIdx.x * 256 + threadIdx.x;
  const int row  = gtid >> 6;          // one wave per row
  const int lane = threadIdx.x & 63;
  if (row >= NN) return;

  const float4 v = reinterpret_cast<const float4*>(Z + (size_t)row * DD)[lane];
  float ss = v.x * v.x + v.y * v.y + v.z * v.z + v.w * v.w;
#pragma unroll
  for (int off = 32; off > 0; off >>= 1) ss += __shfl_xor(ss, off);
  if (lane == 0) rnorm[row] = 1.0f / fmaxf(sqrtf(ss), 1e-8f);

  const float f[4] = {v.x, v.y, v.z, v.w};
  unsigned short h[4];
#pragma unroll
  for (int i = 0; i < 4; ++i) {
    _Float16 x = (_Float16)f[i];       // RNE
    h[i] = *reinterpret_cast<unsigned short*>(&x);
  }
  reinterpret_cast<ushort4*>(Zh + (size_t)row * DD)[lane] =
      make_ushort4(h[0], h[1], h[2], h[3]);
}

// LDS: f16 staging (16 KB) union'd with bf16 wave-private transpose buffers
struct __attribute__((aligned(16))) SharedT {
  union {
    struct {
      unsigned short Ah[BM * BK];     // f16 bits, 8 KB
      unsigned short Bh[BN * BK];     // 8 KB
    } t;
    unsigned short tbuf[4][32][68];   // bf16 bits; 17.4 KB
  };
};

// --- upper-tri Gram GEMM (single f16 MFMA pass) + gated dual epilogue ---
__global__ __launch_bounds__(256, 2) void gram_kernel(
    const unsigned short* __restrict__ Zh,
    const float* __restrict__ rnorm,
    const int* __restrict__ batch,
    float* __restrict__ outA,
    float* __restrict__ outS) {
  __shared__ SharedT sh;
  __shared__ float sRnA[BM];
  __shared__ float sRnB[BN];
  __shared__ int   sBtA[BM];
  __shared__ int   sBtB[BN];

  const int tid  = threadIdx.x;
  const int lane = tid & 63;
  const int wid  = tid >> 6;
  const int wr   = wid >> 1;   // 2x2 wave grid, each wave 64x64
  const int wc   = wid & 1;

  // XCD-aware swizzle (2080 % 8 == 0 -> bijective)
  const int nb  = NN / BM;                 // 64
  const int nwg = nb * (nb + 1) / 2;       // 2080
  const int bid = blockIdx.x;
  const int idx = (bid & 7) * (nwg >> 3) + (bid >> 3);

  // triangular decode: idx -> (brow <= bcol)
  int bcol = (int)((sqrtf(8.0f * (float)idx + 1.0f) - 1.0f) * 0.5f);
  while ((bcol + 1) * (bcol + 2) / 2 <= idx) ++bcol;
  while (bcol * (bcol + 1) / 2 > idx) --bcol;
  const int brow = idx - bcol * (bcol + 1) / 2;
  const int row0 = brow * BM, col0 = bcol * BN;

  // sorted batch: same-batch pair exists iff row-range max >= col-range min
  const bool hasS = (batch[row0 + BM - 1] >= batch[col0]);

  if (tid < 128) {
    sRnA[tid] = rnorm[row0 + tid];
    sBtA[tid] = batch[row0 + tid];
  } else {
    const int t = tid - 128;
    sRnB[t] = rnorm[col0 + t];
    sBtB[t] = batch[col0 + t];
  }

  f32x4 acc[4][4] = {};

  const int lr = lane >> 4;   // 0..3  (k-chunk)
  const int lc = lane & 15;   // 0..15 (row within fragment)

  for (int kt = 0; kt < DD / BK; ++kt) {
    const int k0 = kt * BK;
    // stage 2 tiles of 128x32 f16, XOR-swizzled on the GLOBAL side
#pragma unroll
    for (int c = 0; c < 2; ++c) {
      const int ci  = c * 256 + tid;            // 16B-chunk index [0,512)
      const int r   = ci >> 2;                  // tile-local row
      const int ch  = ci & 3;
      const int chg = ch ^ ((r >> 1) & 3);      // swizzle involution
      const int base = (c * 256 + wid * 64) * 16;  // wave-uniform LDS byte base
      const size_t ga = (size_t)(row0 + r) * DD + k0 + chg * 8;
      const size_t gb = (size_t)(col0 + r) * DD + k0 + chg * 8;
      gload_lds16(Zh + ga, (char*)sh.t.Ah + base);
      gload_lds16(Zh + gb, (char*)sh.t.Bh + base);
    }
    __syncthreads();   // drains vmcnt before any wave reads LDS

    // single-pass f16 MFMA (exact products, f32 accumulate)
    f16x8 fa[4], fb[4];
#pragma unroll
    for (int m = 0; m < 4; ++m) {
      const int rA = wr * 64 + m * 16 + lc;
      const int off = rA * BK + ((lr ^ ((rA >> 1) & 3)) << 3);
      fa[m] = *reinterpret_cast<const f16x8*>(&sh.t.Ah[off]);
    }
#pragma unroll
    for (int n = 0; n < 4; ++n) {
      const int rB = wc * 64 + n * 16 + lc;
      const int off = rB * BK + ((lr ^ ((rB >> 1) & 3)) << 3);
      fb[n] = *reinterpret_cast<const f16x8*>(&sh.t.Bh[off]);
    }
#pragma unroll
    for (int m = 0; m < 4; ++m)
#pragma unroll
      for (int n = 0; n < 4; ++n)
        acc[m][n] = __builtin_amdgcn_mfma_f32_16x16x32_f16(fa[m], fb[n], acc[m][n], 0, 0, 0);
    __syncthreads();   // staging consumed; also protects tbuf overlay below
  }

  const bool mirror = (brow != bcol);

  // Barrier-free epilogue: 2 passes of 32 rows; bf16 parking, regular f32x4
  // stores (L2 write-combining; Z is f16 4MB -> no thrash risk).
  unsigned short* T = &sh.tbuf[wid][0][0];   // [32][68] bf16 bits

  for (int p = 0; p < 2; ++p) {
    // dump 32x64 (acc m = 2p, 2p+1) as bf16 (RNE)
#pragma unroll
    for (int mm = 0; mm < 2; ++mm) {
#pragma unroll
      for (int n = 0; n < 4; ++n)
#pragma unroll
        for (int j = 0; j < 4; ++j) {
          __hip_bfloat16 h = __float2bfloat16(acc[p * 2 + mm][n][j]);
          T[(mm * 16 + lr * 4 + j) * 68 + n * 16 + lc] =
              *reinterpret_cast<unsigned short*>(&h);
        }
    }
    // (same-wave ds_write->ds_read: compiler inserts lgkmcnt; no barrier)

    // phase A: 4 rows x 64 cols per iter; 256B contiguous per 16-lane group
#pragma unroll 4
    for (int i = 0; i < 8; ++i) {
      const int r  = i * 4 + (lane >> 4);        // 0..31
      const int c4 = (lane & 15) * 4;            // 0,4,...,60
      const int rl = wr * 64 + p * 32 + r;
      const int cl = wc * 64 + c4;
      const ushort4 gu = *reinterpret_cast<const ushort4*>(&T[r * 68 + c4]);
      const float gv[4] = {bfbits2f(gu.x), bfbits2f(gu.y),
                           bfbits2f(gu.z), bfbits2f(gu.w)};
      f32x4 a4;
#pragma unroll
      for (int k = 0; k < 4; ++k)
        a4[k] = __builtin_amdgcn_rcpf(1.0f + __expf(-gv[k]));
      const size_t o = (size_t)(row0 + rl) * NN + (col0 + cl);
      *reinterpret_cast<f32x4*>(outA + o) = a4;
      if (hasS) {
        const float4 rnB = *reinterpret_cast<const float4*>(&sRnB[cl]);
        const int4   btB = *reinterpret_cast<const int4*>(&sBtB[cl]);
        const float rnA = sRnA[rl];
        const int   btA = sBtA[rl];
        const int   bb[4] = {btB.x, btB.y, btB.z, btB.w};
        const float rb[4] = {rnB.x, rnB.y, rnB.z, rnB.w};
        f32x4 s4;
#pragma unroll
        for (int k = 0; k < 4; ++k)
          s4[k] = (btA == bb[k]) ? gv[k] * rnA * rb[k] : 0.0f;
        *reinterpret_cast<f32x4*>(outS + o) = s4;
      }
    }

    // phase B: mirrored; 8-lane groups write 128B full lines as f32x4
    if (mirror) {
#pragma unroll 4
      for (int i = 0; i < 8; ++i) {
        const int c  = i * 8 + (lane >> 3);      // orig col (mirror row) 0..63
        const int r4 = (lane & 7) * 4;           // orig row base 0..28
        const int rl = wr * 64 + p * 32 + r4;
        const int cl = wc * 64 + c;
        float gv[4];
#pragma unroll
        for (int k = 0; k < 4; ++k) gv[k] = bfbits2f(T[(r4 + k) * 68 + c]);
        f32x4 a4;
#pragma unroll
        for (int k = 0; k < 4; ++k)
          a4[k] = __builtin_amdgcn_rcpf(1.0f + __expf(-gv[k]));
        const size_t o = (size_t)(col0 + cl) * NN + (row0 + rl);
        *reinterpret_cast<f32x4*>(outA + o) = a4;
        if (hasS) {
          const float4 rnA4 = *reinterpret_cast<const float4*>(&sRnA[rl]);
          const int4   btA4 = *reinterpret_cast<const int4*>(&sBtA[rl]);
          const float rnB = sRnB[cl];
          const int   btB = sBtB[cl];
          const int   ba[4] = {btA4.x, btA4.y, btA4.z, btA4.w};
          const float ra[4] = {rnA4.x, rnA4.y, rnA4.z, rnA4.w};
          f32x4 s4;
#pragma unroll
          for (int k = 0; k < 4; ++k)
            s4[k] = (ba[k] == btB) ? gv[k] * ra[k] * rnB : 0.0f;
          *reinterpret_cast<f32x4*>(outS + o) = s4;
        }
      }
    }
  }
}

extern "C" void kernel_launch(void* const* d_in, const int* in_sizes, int n_in,
                              void* d_out, int out_size, void* d_ws, size_t ws_size,
                              hipStream_t stream) {
  const float* Z     = (const float*)d_in[0];
  const int*   batch = (const int*)d_in[1];
  float* out  = (float*)d_out;
  float* outS = out + (size_t)NN * NN;

  unsigned short* Zh = (unsigned short*)d_ws;            // f16 bits, 4 MB
  float* rnorm = (float*)(Zh + (size_t)NN * DD);

  // zero outS at pure-store peak; gram writes only same-batch-capable tiles
  hipMemsetAsync(outS, 0, (size_t)NN * NN * sizeof(float), stream);

  prep_kernel<<<NN / 4, 256, 0, stream>>>(Z, Zh, rnorm);

  const int nb = NN / BM;                 // 64
  const int nblocks = nb * (nb + 1) / 2;  // 2080
  gram_kernel<<<dim3(nblocks), 256, 0, stream>>>(Zh, rnorm, batch, out, outS);
}

// Round 24
// 99.678 us; speedup vs baseline: 1.3056x; 1.2727x over previous
//
#include <hip/hip_runtime.h>
#include <hip/hip_bf16.h>

#define NN 8192
#define DD 256
#define BM 128
#define BN 128
#define BK 32

typedef _Float16 f16x8 __attribute__((ext_vector_type(8)));
typedef float f32x4 __attribute__((ext_vector_type(4)));

__device__ inline void gload_lds16(const void* g, void* l) {
  __builtin_amdgcn_global_load_lds(
      (const __attribute__((address_space(1))) void*)g,
      (__attribute__((address_space(3))) void*)l, 16, 0, 0);
}

__device__ __forceinline__ float bfbits2f(unsigned short u) {
  return __uint_as_float(((unsigned)u) << 16);
}

// ---------------- prep: rnorm + f16 cast ----------------
__global__ __launch_bounds__(256) void prep_kernel(
    const float* __restrict__ Z,
    unsigned short* __restrict__ Zh,   // f16 bits
    float* __restrict__ rnorm) {
  const int gtid = blockIdx.x * 256 + threadIdx.x;
  const int row  = gtid >> 6;          // one wave per row
  const int lane = threadIdx.x & 63;
  if (row >= NN) return;

  const float4 v = reinterpret_cast<const float4*>(Z + (size_t)row * DD)[lane];
  float ss = v.x * v.x + v.y * v.y + v.z * v.z + v.w * v.w;
#pragma unroll
  for (int off = 32; off > 0; off >>= 1) ss += __shfl_xor(ss, off);
  if (lane == 0) rnorm[row] = 1.0f / fmaxf(sqrtf(ss), 1e-8f);

  const float f[4] = {v.x, v.y, v.z, v.w};
  unsigned short h[4];
#pragma unroll
  for (int i = 0; i < 4; ++i) {
    _Float16 x = (_Float16)f[i];       // RNE
    h[i] = *reinterpret_cast<unsigned short*>(&x);
  }
  reinterpret_cast<ushort4*>(Zh + (size_t)row * DD)[lane] =
      make_ushort4(h[0], h[1], h[2], h[3]);
}

// LDS: f16 staging (16 KB) union'd with bf16 wave-private transpose buffers
struct __attribute__((aligned(16))) SharedT {
  union {
    struct {
      unsigned short Ah[BM * BK];     // f16 bits, 8 KB
      unsigned short Bh[BN * BK];     // 8 KB
    } t;
    unsigned short tbuf[4][32][68];   // bf16 bits; 17.4 KB
  };
};

// --- heterogeneous grid: even bids = gram tile (f16 MFMA + NT epilogue),
//     odd bids = pure zero-fill of outS where no same-batch pair exists ---
__global__ __launch_bounds__(256, 2) void gram_kernel(
    const unsigned short* __restrict__ Zh,
    const float* __restrict__ rnorm,
    const int* __restrict__ batch,
    float* __restrict__ outA,
    float* __restrict__ outS) {
  __shared__ SharedT sh;
  __shared__ float sRnA[BM];
  __shared__ float sRnB[BN];
  __shared__ int   sBtA[BM];
  __shared__ int   sBtB[BN];

  const int tid  = threadIdx.x;
  const int lane = tid & 63;
  const int wid  = tid >> 6;
  const int wr   = wid >> 1;   // 2x2 wave grid, each wave 64x64
  const int wc   = wid & 1;

  // tile id + role; XCD-aware swizzle on tile id (2080 % 8 == 0 -> bijective)
  const int nb  = NN / BM;                 // 64
  const int nwg = nb * (nb + 1) / 2;       // 2080
  const int tb  = blockIdx.x >> 1;
  const bool isFill = (blockIdx.x & 1);
  const int idx = (tb & 7) * (nwg >> 3) + (tb >> 3);

  // triangular decode: idx -> (brow <= bcol)
  int bcol = (int)((sqrtf(8.0f * (float)idx + 1.0f) - 1.0f) * 0.5f);
  while ((bcol + 1) * (bcol + 2) / 2 <= idx) ++bcol;
  while (bcol * (bcol + 1) / 2 > idx) --bcol;
  const int brow = idx - bcol * (bcol + 1) / 2;
  const int row0 = brow * BM, col0 = bcol * BN;

  // sorted batch: same-batch pair exists iff row-range max >= col-range min
  const bool hasS = (batch[row0 + BM - 1] >= batch[col0]);

  if (isFill) {
    // pure fill block: zero outS tile + mirror where gram won't write it.
    // hasS tiles (incl. all diagonals) are fully written by the gram block.
    if (hasS) return;
    const f32x4 z4 = {0.0f, 0.0f, 0.0f, 0.0f};
    const int r8 = tid >> 5;            // 0..7
    const int c4 = (tid & 31) * 4;      // 0..124
#pragma unroll 4
    for (int i = 0; i < 16; ++i) {
      const int r = i * 8 + r8;
      *reinterpret_cast<f32x4*>(outS + (size_t)(row0 + r) * NN + col0 + c4) = z4;
      *reinterpret_cast<f32x4*>(outS + (size_t)(col0 + r) * NN + row0 + c4) = z4;
    }
    return;
  }

  if (tid < 128) {
    sRnA[tid] = rnorm[row0 + tid];
    sBtA[tid] = batch[row0 + tid];
  } else {
    const int t = tid - 128;
    sRnB[t] = rnorm[col0 + t];
    sBtB[t] = batch[col0 + t];
  }

  f32x4 acc[4][4] = {};

  const int lr = lane >> 4;   // 0..3  (k-chunk)
  const int lc = lane & 15;   // 0..15 (row within fragment)

  for (int kt = 0; kt < DD / BK; ++kt) {
    const int k0 = kt * BK;
    // stage 2 tiles of 128x32 f16, XOR-swizzled on the GLOBAL side
#pragma unroll
    for (int c = 0; c < 2; ++c) {
      const int ci  = c * 256 + tid;            // 16B-chunk index [0,512)
      const int r   = ci >> 2;                  // tile-local row
      const int ch  = ci & 3;
      const int chg = ch ^ ((r >> 1) & 3);      // swizzle involution
      const int base = (c * 256 + wid * 64) * 16;  // wave-uniform LDS byte base
      const size_t ga = (size_t)(row0 + r) * DD + k0 + chg * 8;
      const size_t gb = (size_t)(col0 + r) * DD + k0 + chg * 8;
      gload_lds16(Zh + ga, (char*)sh.t.Ah + base);
      gload_lds16(Zh + gb, (char*)sh.t.Bh + base);
    }
    __syncthreads();   // drains vmcnt before any wave reads LDS

    // single-pass f16 MFMA (exact products, f32 accumulate)
    f16x8 fa[4], fb[4];
#pragma unroll
    for (int m = 0; m < 4; ++m) {
      const int rA = wr * 64 + m * 16 + lc;
      const int off = rA * BK + ((lr ^ ((rA >> 1) & 3)) << 3);
      fa[m] = *reinterpret_cast<const f16x8*>(&sh.t.Ah[off]);
    }
#pragma unroll
    for (int n = 0; n < 4; ++n) {
      const int rB = wc * 64 + n * 16 + lc;
      const int off = rB * BK + ((lr ^ ((rB >> 1) & 3)) << 3);
      fb[n] = *reinterpret_cast<const f16x8*>(&sh.t.Bh[off]);
    }
#pragma unroll
    for (int m = 0; m < 4; ++m)
#pragma unroll
      for (int n = 0; n < 4; ++n)
        acc[m][n] = __builtin_amdgcn_mfma_f32_16x16x32_f16(fa[m], fb[n], acc[m][n], 0, 0, 0);
    __syncthreads();   // staging consumed; also protects tbuf overlay below
  }

  const bool mirror = (brow != bcol);

  // Barrier-free epilogue: 2 passes of 32 rows; bf16 parking, f32x4 NT stores.
  unsigned short* T = &sh.tbuf[wid][0][0];   // [32][68] bf16 bits

  for (int p = 0; p < 2; ++p) {
    // dump 32x64 (acc m = 2p, 2p+1) as bf16 (RNE)
#pragma unroll
    for (int mm = 0; mm < 2; ++mm) {
#pragma unroll
      for (int n = 0; n < 4; ++n)
#pragma unroll
        for (int j = 0; j < 4; ++j) {
          __hip_bfloat16 h = __float2bfloat16(acc[p * 2 + mm][n][j]);
          T[(mm * 16 + lr * 4 + j) * 68 + n * 16 + lc] =
              *reinterpret_cast<unsigned short*>(&h);
        }
    }
    // (same-wave ds_write->ds_read: compiler inserts lgkmcnt; no barrier)

    // phase A: 4 rows x 64 cols per iter; 256B contiguous per 16-lane group
#pragma unroll 4
    for (int i = 0; i < 8; ++i) {
      const int r  = i * 4 + (lane >> 4);        // 0..31
      const int c4 = (lane & 15) * 4;            // 0,4,...,60
      const int rl = wr * 64 + p * 32 + r;
      const int cl = wc * 64 + c4;
      const ushort4 gu = *reinterpret_cast<const ushort4*>(&T[r * 68 + c4]);
      const float gv[4] = {bfbits2f(gu.x), bfbits2f(gu.y),
                           bfbits2f(gu.z), bfbits2f(gu.w)};
      f32x4 a4;
#pragma unroll
      for (int k = 0; k < 4; ++k)
        a4[k] = __builtin_amdgcn_rcpf(1.0f + __expf(-gv[k]));
      const size_t o = (size_t)(row0 + rl) * NN + (col0 + cl);
      __builtin_nontemporal_store(a4, reinterpret_cast<f32x4*>(outA + o));
      if (hasS) {
        const float4 rnB = *reinterpret_cast<const float4*>(&sRnB[cl]);
        const int4   btB = *reinterpret_cast<const int4*>(&sBtB[cl]);
        const float rnA = sRnA[rl];
        const int   btA = sBtA[rl];
        const int   bb[4] = {btB.x, btB.y, btB.z, btB.w};
        const float rb[4] = {rnB.x, rnB.y, rnB.z, rnB.w};
        f32x4 s4;
#pragma unroll
        for (int k = 0; k < 4; ++k)
          s4[k] = (btA == bb[k]) ? gv[k] * rnA * rb[k] : 0.0f;
        __builtin_nontemporal_store(s4, reinterpret_cast<f32x4*>(outS + o));
      }
    }

    // phase B: mirrored; 8-lane groups write 128B full lines as f32x4
    if (mirror) {
#pragma unroll 4
      for (int i = 0; i < 8; ++i) {
        const int c  = i * 8 + (lane >> 3);      // orig col (mirror row) 0..63
        const int r4 = (lane & 7) * 4;           // orig row base 0..28
        const int rl = wr * 64 + p * 32 + r4;
        const int cl = wc * 64 + c;
        float gv[4];
#pragma unroll
        for (int k = 0; k < 4; ++k) gv[k] = bfbits2f(T[(r4 + k) * 68 + c]);
        f32x4 a4;
#pragma unroll
        for (int k = 0; k < 4; ++k)
          a4[k] = __builtin_amdgcn_rcpf(1.0f + __expf(-gv[k]));
        const size_t o = (size_t)(col0 + cl) * NN + (row0 + rl);
        __builtin_nontemporal_store(a4, reinterpret_cast<f32x4*>(outA + o));
        if (hasS) {
          const float4 rnA4 = *reinterpret_cast<const float4*>(&sRnA[rl]);
          const int4   btA4 = *reinterpret_cast<const int4*>(&sBtA[rl]);
          const float rnB = sRnB[cl];
          const int   btB = sBtB[cl];
          const int   ba[4] = {btA4.x, btA4.y, btA4.z, btA4.w};
          const float ra[4] = {rnA4.x, rnA4.y, rnA4.z, rnA4.w};
          f32x4 s4;
#pragma unroll
          for (int k = 0; k < 4; ++k)
            s4[k] = (ba[k] == btB) ? gv[k] * ra[k] * rnB : 0.0f;
          __builtin_nontemporal_store(s4, reinterpret_cast<f32x4*>(outS + o));
        }
      }
    }
  }
}

extern "C" void kernel_launch(void* const* d_in, const int* in_sizes, int n_in,
                              void* d_out, int out_size, void* d_ws, size_t ws_size,
                              hipStream_t stream) {
  const float* Z     = (const float*)d_in[0];
  const int*   batch = (const int*)d_in[1];
  float* out  = (float*)d_out;
  float* outS = out + (size_t)NN * NN;

  unsigned short* Zh = (unsigned short*)d_ws;            // f16 bits, 4 MB
  float* rnorm = (float*)(Zh + (size_t)NN * DD);

  prep_kernel<<<NN / 4, 256, 0, stream>>>(Z, Zh, rnorm);

  // heterogeneous grid: 2080 gram tiles (even bids) + 2080 fill blocks (odd)
  const int nb = NN / BM;                 // 64
  const int nblocks = nb * (nb + 1) / 2;  // 2080
  gram_kernel<<<dim3(nblocks * 2), 256, 0, stream>>>(Zh, rnorm, batch, out,
                                                     outS);
}